// Round 11
// baseline (129.906 us; speedup 1.0000x reference)
//
#include <hip/hip_runtime.h>
#include <hip/hip_bf16.h>

// B=16, T=2048, C=384, H=64. out = softmax((x Wq)(x Wk)^T / sqrt(C)) (x Wv)
// ws (bf16): Qb[32768*64] | Kb[32768*64] | Vt[16][64][2048] | Wt[6*192*64]
// R14: flash PV waves re-split over (q-half x kh-chunk). Old: each PV wave
// owned a q-quarter and read the WHOLE V tile (4x cross-wave redundancy in
// va reads; 40KB/block-iter PV reads). New: wave (qg,kg) handles q-tiles
// {2qg,2qg+1} at kh=kg only -> 2 pb + 4 va = 6 reads (was 10), same 10
// MFMA. CU-iter LDS traffic 112->80 KB (-29%) -- after R9/R13 raised
// occupancy, LDS throughput is the plausible binder. O/l become k-partial
// across the kg pair: merged once in the epilogue via LDS (kg=1 writes raw
// partials, kg=0 adds + normalizes; +2 barriers total).

typedef __bf16 bf16;
typedef __attribute__((ext_vector_type(8))) __bf16 bf16x8;
typedef __attribute__((ext_vector_type(4))) __bf16 bf16x4;
typedef __attribute__((ext_vector_type(4))) float f32x4;

#define SCALE_LOG2E (0.051031036307982884f * 1.4426950408889634f)

// swizzled element pointer into a [64][64] bf16 tile (128 B rows):
// byte = row*128 + (cbyte ^ ((row&7)<<4)); bijective, keeps 16B/8B alignment.
__device__ __forceinline__ bf16* tp(bf16* base, int row, int cbyte) {
    return (bf16*)((char*)base + row * 128 + (cbyte ^ ((row & 7) << 4)));
}

// ---------------------------------------------------------------------------
// Kernel 0: pack W^T, Wt[ck][h][c'] (c = ck*64+c', h in [0,192) = Wq|Wk|Wv).
// ---------------------------------------------------------------------------
__global__ void pack_w(const float* __restrict__ Wq, const float* __restrict__ Wk,
                       const float* __restrict__ Wv, bf16* __restrict__ Wt) {
    int idx = blockIdx.x * 256 + threadIdx.x;      // 0..73727
    int cc = idx & 63;
    int hh = (idx >> 6) % 192;
    int ck = idx / 12288;
    const float* W = (hh < 64) ? Wq : (hh < 128 ? Wk : Wv);
    Wt[idx] = (bf16)W[(ck * 64 + cc) * 64 + (hh & 63)];
}

// ---------------------------------------------------------------------------
// Kernel 1: QKV projection (R13 version: 512 thr, 8 waves, wave (rg,cg)).
// ---------------------------------------------------------------------------
__global__ __launch_bounds__(512) void qkv_proj(const float* __restrict__ x,
                                                const bf16* __restrict__ Wt,
                                                bf16* __restrict__ Qb,
                                                bf16* __restrict__ Kb,
                                                bf16* __restrict__ Vtg) {
    __shared__ __align__(16) bf16 Xs[2][64 * 72];
    __shared__ __align__(16) bf16 Ws[2][192 * 72];

    const int tid = threadIdx.x;
    const int wv = tid >> 6, lane = tid & 63, quad = lane >> 4, l16 = lane & 15;
    const int rg = wv >> 2, cg = wv & 3;
    const int row0 = blockIdx.x * 64;

    f32x4 acc[6];                                  // [rt][j] -> acc[rt*3+j]
#pragma unroll
    for (int n = 0; n < 6; n++) acc[n] = (f32x4){0.f, 0.f, 0.f, 0.f};

    float4 xpre[2];
    bf16x8 wpre[3];
#pragma unroll
    for (int k = 0; k < 2; k++) {
        int g = tid + k * 512;
        xpre[k] = *(const float4*)(x + (long)(row0 + (g >> 4)) * 384 + (g & 15) * 4);
    }
#pragma unroll
    for (int k = 0; k < 3; k++)
        wpre[k] = *(const bf16x8*)(Wt + (tid + k * 512) * 8);

    for (int ck = 0; ck < 6; ck++) {
        bf16* Xc = Xs[ck & 1];
        bf16* Wc = Ws[ck & 1];
#pragma unroll
        for (int k = 0; k < 2; k++) {
            int g = tid + k * 512;
            float4 xv = xpre[k];
            *(bf16x4*)(&Xc[(g >> 4) * 72 + (g & 15) * 4]) =
                (bf16x4){(bf16)xv.x, (bf16)xv.y, (bf16)xv.z, (bf16)xv.w};
        }
#pragma unroll
        for (int k = 0; k < 3; k++) {
            int g = tid + k * 512;
            *(bf16x8*)(&Wc[(g >> 3) * 72 + (g & 7) * 8]) = wpre[k];
        }
        if (ck < 5) {
#pragma unroll
            for (int k = 0; k < 2; k++) {
                int g = tid + k * 512;
                xpre[k] = *(const float4*)(x + (long)(row0 + (g >> 4)) * 384 +
                                           (ck + 1) * 64 + (g & 15) * 4);
            }
#pragma unroll
            for (int k = 0; k < 3; k++)
                wpre[k] = *(const bf16x8*)(Wt + (ck + 1) * 12288 + (tid + k * 512) * 8);
        }
        __syncthreads();
#pragma unroll
        for (int kh = 0; kh < 2; kh++) {
            bf16x8 bb[3];
#pragma unroll
            for (int j = 0; j < 3; j++)
                bb[j] = *(bf16x8*)(&Wc[((cg * 3 + j) * 16 + l16) * 72 + kh * 32 + quad * 8]);
#pragma unroll
            for (int rt = 0; rt < 2; rt++) {
                bf16x8 a = *(bf16x8*)(&Xc[(rg * 32 + rt * 16 + l16) * 72 + kh * 32 + quad * 8]);
#pragma unroll
                for (int j = 0; j < 3; j++)
                    acc[rt * 3 + j] = __builtin_amdgcn_mfma_f32_16x16x32_bf16(
                        a, bb[j], acc[rt * 3 + j], 0, 0, 0);
            }
        }
    }

    // epilogue: scatter acc (n = cg*3+j wave-uniform) into staging buffers
    __syncthreads();
#pragma unroll
    for (int rt = 0; rt < 2; rt++) {
#pragma unroll
        for (int j = 0; j < 3; j++) {
            const int n = cg * 3 + j;
            const int drow = rg * 32 + rt * 16 + quad * 4;
#pragma unroll
            for (int r = 0; r < 4; r++) {
                float v = acc[rt * 3 + j][r];
                if (n < 4)
                    Xs[0][(drow + r) * 72 + n * 16 + l16] = (bf16)(v * SCALE_LOG2E);
                else if (n < 8)
                    Xs[1][(drow + r) * 72 + (n - 4) * 16 + l16] = (bf16)v;
                else
                    Ws[0][((n - 8) * 16 + l16) * 72 + drow + r] = (bf16)v;
            }
        }
    }
    __syncthreads();
    const int b = row0 >> 11, t0 = row0 & 2047;
    const int srow = tid >> 3, scb = (tid & 7) * 8;
    *(bf16x8*)(Qb + (long)(row0 + srow) * 64 + scb) =
        *(bf16x8*)(&Xs[0][srow * 72 + scb]);
    *(bf16x8*)(Kb + (long)(row0 + srow) * 64 + scb) =
        *(bf16x8*)(&Xs[1][srow * 72 + scb]);
    *(bf16x8*)(Vtg + (long)(b * 64 + srow) * 2048 + t0 + scb) =
        *(bf16x8*)(&Ws[0][srow * 72 + scb]);
}

// ---------------------------------------------------------------------------
// Kernel 2: flash attention, 512 blocks x 512 thr (8 waves), 32 k-iters.
// Waves 0-3 (S): key-subtile wv; K-direct frags; exp2; Ps write; V staging.
// Waves 4-7 (PV): wave (qg,kg)=( (wv-4)>>1, (wv-4)&1 ): q-tiles {2qg,2qg+1},
// kh=kg only; O/l k-partial, merged in epilogue.
// LDS 32768 B: Qs/Ps0 @0 | VsA 2x8192 @8192 | Ps1 @24576
//   epilogue overlay: Om [64][68] f32 @0 (17408) | Lp [64] f32 @17408.
// Parity: V commit [kt&1] (S), PV reads [(kt+1)&1]=V[kt-1]; Ps write
// [kt&1] (S), PV reads [(kt-1)&1]; kf reg-dbuf under unroll 2.
// ---------------------------------------------------------------------------
__global__ __launch_bounds__(512) void flash_attn(const bf16* __restrict__ Qb,
                                                  const bf16* __restrict__ Kb,
                                                  const bf16* __restrict__ Vtg,
                                                  float* __restrict__ out) {
    __shared__ __align__(16) char smem[32768];
    bf16* Qs  = (bf16*)smem;                  // [64][64]; Ps0 overlays after hoist
    bf16* Ps0 = Qs;
    bf16* Ps1 = (bf16*)(smem + 24576);

    const int tid = threadIdx.x;
    const int wv = tid >> 6, lane = tid & 63, quad = lane >> 4, l16 = lane & 15;
    const bool sw = (wv < 4);                 // S/staging waves
    const int pq = wv - 4;                    // PV wave index 0..3
    const int qg = pq >> 1, kg = pq & 1;      // q-half, kh-chunk
    // XCD-aware swizzle: keep a batch's K/V resident in one XCD's L2.
    const int i0 = blockIdx.x;
    const int b = (i0 & 7) + 8 * ((i0 >> 3) >> 5);
    const int qt = (i0 >> 3) & 31;

    const bf16* Qg = Qb + (long)(b * 2048 + qt * 64) * 64;
    const bf16* Kg = Kb + (long)b * 2048 * 64;
    const bf16* Vg = Vtg + (long)b * 64 * 2048;

    // stage Q tile [64][64] (swizzled): 512 thr x 16B
    const int qrow = tid >> 3, qcb = (tid & 7) * 16;
    *(bf16x8*)tp(Qs, qrow, qcb) = *(const bf16x8*)(Qg + qrow * 64 + (qcb >> 1));

    // V staging geometry (S-waves, tid<256): 256 lanes x 32B
    const int vrow = tid >> 2, vcb = (tid & 3) * 32;
    // K fragment base (S-waves): ka[j]=K[kt*64+wv*16+l16][kh*32+quad*8+j]
    const bf16* Kfb = Kg + (wv * 16 + l16) * 64 + quad * 8;

    bf16x8 kf[2][2], vp[2];
    if (sw) {
        kf[0][0] = *(const bf16x8*)(Kfb);
        kf[0][1] = *(const bf16x8*)(Kfb + 32);
        vp[0] = *(const bf16x8*)(Vg + (long)vrow * 2048 + (vcb >> 1));
        vp[1] = *(const bf16x8*)(Vg + (long)vrow * 2048 + (vcb >> 1) + 8);
    }

    f32x4 o[2][4], ol[2];
#pragma unroll
    for (int n = 0; n < 2; n++) {
#pragma unroll
        for (int m = 0; m < 4; m++) o[n][m] = (f32x4){0.f, 0.f, 0.f, 0.f};
        ol[n] = (f32x4){0.f, 0.f, 0.f, 0.f};
    }

    __syncthreads();            // Qs staged
    // hoist Q^T b-frags (S-waves only; loop-invariant)
    bf16x8 qb[4][2];
    if (sw) {
#pragma unroll
        for (int nt = 0; nt < 4; nt++)
#pragma unroll
            for (int kh = 0; kh < 2; kh++)
                qb[nt][kh] = *(bf16x8*)tp(Qs, nt * 16 + l16, kh * 64 + quad * 16);
    }
    __syncthreads();            // hoist done before Ps0 (=Qs) writes

    const bf16 one = (bf16)1.0f;
    const bf16x8 ones = {one, one, one, one, one, one, one, one};

#pragma unroll 2
    for (int kt = 0; kt < 32; kt++) {
        bf16* Vn = (bf16*)(smem + 8192 + (kt & 1) * 8192);        // commit V[kt]
        bf16* Vp = (bf16*)(smem + 8192 + ((kt + 1) & 1) * 8192);  // PV src: V[kt-1]
        bf16* Pw = (kt & 1) ? Ps1 : Ps0;                          // write Ps[kt]
        bf16* Pr = (kt & 1) ? Ps0 : Ps1;                          // read  Ps[kt-1]

        if (sw) {
            // commit prefetched V tile (region not read this iteration)
            *(bf16x8*)tp(Vn, vrow, vcb)      = vp[0];
            *(bf16x8*)tp(Vn, vrow, vcb + 16) = vp[1];
            // issue next prefetches (stay in flight across the barrier)
            if (kt < 31) {
                kf[(kt + 1) & 1][0] = *(const bf16x8*)(Kfb + (long)(kt + 1) * 4096);
                kf[(kt + 1) & 1][1] = *(const bf16x8*)(Kfb + (long)(kt + 1) * 4096 + 32);
                vp[0] = *(const bf16x8*)(Vg + (long)vrow * 2048 + (kt + 1) * 64 + (vcb >> 1));
                vp[1] = *(const bf16x8*)(Vg + (long)vrow * 2048 + (kt + 1) * 64 + (vcb >> 1) + 8);
            }
            // S^T[kt] = K Q^T : this wave's key subtile (m=wv), all 4 q-tiles
            f32x4 s[4];
#pragma unroll
            for (int nt = 0; nt < 4; nt++) s[nt] = (f32x4){0.f, 0.f, 0.f, 0.f};
            __builtin_amdgcn_s_setprio(1);
#pragma unroll
            for (int kh = 0; kh < 2; kh++) {
                bf16x8 ka = kf[kt & 1][kh];
#pragma unroll
                for (int nt = 0; nt < 4; nt++)
                    s[nt] = __builtin_amdgcn_mfma_f32_16x16x32_bf16(ka, qb[nt][kh], s[nt], 0, 0, 0);
            }
            __builtin_amdgcn_s_setprio(0);
            // p = exp2(s), pack 4 -> b64 store into Ps[kt]
#pragma unroll
            for (int nt = 0; nt < 4; nt++) {
                bf16x4 pp;
#pragma unroll
                for (int r = 0; r < 4; r++)
                    pp[r] = (bf16)__builtin_amdgcn_exp2f(s[nt][r]);
                *(bf16x4*)tp(Pw, nt * 16 + l16, wv * 32 + quad * 8) = pp;
            }
        } else if (kt) {
            // O^T += V[kt-1]^T Ps[kt-1] : q-tiles {2qg,2qg+1}, kh=kg only
            __builtin_amdgcn_s_setprio(1);
            bf16x8 pb0 = *(bf16x8*)tp(Pr, qg * 32 + l16,      kg * 64 + quad * 16);
            bf16x8 pb1 = *(bf16x8*)tp(Pr, qg * 32 + 16 + l16, kg * 64 + quad * 16);
#pragma unroll
            for (int mt = 0; mt < 4; mt++) {
                bf16x8 va = *(bf16x8*)tp(Vp, mt * 16 + l16, kg * 64 + quad * 16);
                o[0][mt] = __builtin_amdgcn_mfma_f32_16x16x32_bf16(va, pb0, o[0][mt], 0, 0, 0);
                o[1][mt] = __builtin_amdgcn_mfma_f32_16x16x32_bf16(va, pb1, o[1][mt], 0, 0, 0);
            }
            ol[0] = __builtin_amdgcn_mfma_f32_16x16x32_bf16(ones, pb0, ol[0], 0, 0, 0);
            ol[1] = __builtin_amdgcn_mfma_f32_16x16x32_bf16(ones, pb1, ol[1], 0, 0, 0);
            __builtin_amdgcn_s_setprio(0);
        }
        __syncthreads();        // single barrier: publishes V[kt] and Ps[kt]
    }

    // peeled PV[31]: Ps[31] in Ps1, V[31] in parity-1 buffer (@16384)
    if (!sw) {
        bf16* Pr = Ps1;
        bf16* Vp = (bf16*)(smem + 16384);
        bf16x8 pb0 = *(bf16x8*)tp(Pr, qg * 32 + l16,      kg * 64 + quad * 16);
        bf16x8 pb1 = *(bf16x8*)tp(Pr, qg * 32 + 16 + l16, kg * 64 + quad * 16);
#pragma unroll
        for (int mt = 0; mt < 4; mt++) {
            bf16x8 va = *(bf16x8*)tp(Vp, mt * 16 + l16, kg * 64 + quad * 16);
            o[0][mt] = __builtin_amdgcn_mfma_f32_16x16x32_bf16(va, pb0, o[0][mt], 0, 0, 0);
            o[1][mt] = __builtin_amdgcn_mfma_f32_16x16x32_bf16(va, pb1, o[1][mt], 0, 0, 0);
        }
        ol[0] = __builtin_amdgcn_mfma_f32_16x16x32_bf16(ones, pb0, ol[0], 0, 0, 0);
        ol[1] = __builtin_amdgcn_mfma_f32_16x16x32_bf16(ones, pb1, ol[1], 0, 0, 0);
    }

    // epilogue: merge kg-partials, normalize, transpose via LDS.
    // Om [64][68] f32 @0, Lp [64] f32 @17408 (all prior LDS regions dead
    // after the barrier below).
    float* Om = (float*)smem;
    float* Lp = (float*)(smem + 17408);
    __syncthreads();            // peeled reads (Ps1, V parity-1) done
    if (!sw && kg == 1) {       // write raw k-partials
#pragma unroll
        for (int nt = 0; nt < 2; nt++) {
            const int qrow2 = qg * 32 + nt * 16 + l16;
#pragma unroll
            for (int mt = 0; mt < 4; mt++)
                *(f32x4*)(&Om[qrow2 * 68 + mt * 16 + quad * 4]) = o[nt][mt];
            if (quad == 0) Lp[qrow2] = ol[nt][0];
        }
    }
    __syncthreads();
    if (!sw && kg == 0) {       // add own partials, normalize, write back
#pragma unroll
        for (int nt = 0; nt < 2; nt++) {
            const int qrow2 = qg * 32 + nt * 16 + l16;
            const float inv = 1.0f / (ol[nt][0] + Lp[qrow2]);
#pragma unroll
            for (int mt = 0; mt < 4; mt++) {
                f32x4 prev = *(f32x4*)(&Om[qrow2 * 68 + mt * 16 + quad * 4]);
                f32x4 ov;
#pragma unroll
                for (int r = 0; r < 4; r++) ov[r] = (o[nt][mt][r] + prev[r]) * inv;
                *(f32x4*)(&Om[qrow2 * 68 + mt * 16 + quad * 4]) = ov;
            }
        }
    }
    __syncthreads();
    const int orow = tid >> 3, ocf = (tid & 7) * 8;
    float* og = out + (long)(b * 2048 + qt * 64 + orow) * 64 + ocf;
#pragma unroll
    for (int j = 0; j < 2; j++)
        *(float4*)(og + j * 4) = *(float4*)(&Om[orow * 68 + ocf + j * 4]);
}

// ---------------------------------------------------------------------------
extern "C" void kernel_launch(void* const* d_in, const int* in_sizes, int n_in,
                              void* d_out, int out_size, void* d_ws, size_t ws_size,
                              hipStream_t stream) {
    const float* x  = (const float*)d_in[0];
    const float* Wq = (const float*)d_in[1];
    const float* Wk = (const float*)d_in[2];
    const float* Wv = (const float*)d_in[3];
    float* out = (float*)d_out;

    bf16* Qb  = (bf16*)d_ws;           // 32768*64
    bf16* Kb  = Qb + 2097152;
    bf16* Vtg = Kb + 2097152;          // [16][64][2048]
    bf16* Wt  = Vtg + 2097152;         // 6*192*64

    pack_w<<<288, 256, 0, stream>>>(Wq, Wk, Wv, Wt);
    qkv_proj<<<512, 512, 0, stream>>>(x, Wt, Qb, Kb, Vtg);
    flash_attn<<<512, 512, 0, stream>>>(Qb, Kb, Vtg, out);
}

// Round 12
// 121.906 us; speedup vs baseline: 1.0656x; 1.0656x over previous
//
#include <hip/hip_runtime.h>
#include <hip/hip_bf16.h>

// B=16, T=2048, C=384, H=64. out = softmax((x Wq)(x Wk)^T / sqrt(C)) (x Wv)
// ws (bf16): Qb[32768*64] | Kb[32768*64] | Vt[16][64][2048] | Wt[6*192*64]
// R15: revert R14 (kg-split pushed VGPR past 128 -> 1 block/CU cliff, +9us)
// back to the R13 structure, then SUPERSTEP-2: two k-tiles per loop iter,
// ONE barrier per 2 tiles (33 -> ~19 barriers). 4-deep Ps and V rings:
//   Ps[p] @ p*8192 (Ps[0] overlays Qs), Vb[p] @ 32768 + p*8192 (64 KB LDS,
//   2 blocks/CU = 128 KB <= 160). Phase audit: superstep t S-writes phases
//   {2t&3,(2t+1)&3}; PV reads the complementary pair {^2}; each write->read
//   and read->rewrite pair is one-barrier-separated.
// VGPR: only +8 vs R13 (vp 2->4); __launch_bounds__(512,4) pins <=128
// (4 waves/EU) so occupancy cannot cliff (worst case: tiny spill).
// K-direct frags, XOR-swizzled LDS, no-max base-2 softmax unchanged.

typedef __bf16 bf16;
typedef __attribute__((ext_vector_type(8))) __bf16 bf16x8;
typedef __attribute__((ext_vector_type(4))) __bf16 bf16x4;
typedef __attribute__((ext_vector_type(4))) float f32x4;

#define SCALE_LOG2E (0.051031036307982884f * 1.4426950408889634f)

// swizzled element pointer into a [64][64] bf16 tile (128 B rows):
// byte = row*128 + (cbyte ^ ((row&7)<<4)); bijective, keeps 16B/8B alignment.
__device__ __forceinline__ bf16* tp(bf16* base, int row, int cbyte) {
    return (bf16*)((char*)base + row * 128 + (cbyte ^ ((row & 7) << 4)));
}

// ---------------------------------------------------------------------------
// Kernel 0: pack W^T, Wt[ck][h][c'] (c = ck*64+c', h in [0,192) = Wq|Wk|Wv).
// ---------------------------------------------------------------------------
__global__ void pack_w(const float* __restrict__ Wq, const float* __restrict__ Wk,
                       const float* __restrict__ Wv, bf16* __restrict__ Wt) {
    int idx = blockIdx.x * 256 + threadIdx.x;      // 0..73727
    int cc = idx & 63;
    int hh = (idx >> 6) % 192;
    int ck = idx / 12288;
    const float* W = (hh < 64) ? Wq : (hh < 128 ? Wk : Wv);
    Wt[idx] = (bf16)W[(ck * 64 + cc) * 64 + (hh & 63)];
}

// ---------------------------------------------------------------------------
// Kernel 1: QKV projection (R13 version: 512 thr, 8 waves, wave (rg,cg)).
// ---------------------------------------------------------------------------
__global__ __launch_bounds__(512) void qkv_proj(const float* __restrict__ x,
                                                const bf16* __restrict__ Wt,
                                                bf16* __restrict__ Qb,
                                                bf16* __restrict__ Kb,
                                                bf16* __restrict__ Vtg) {
    __shared__ __align__(16) bf16 Xs[2][64 * 72];
    __shared__ __align__(16) bf16 Ws[2][192 * 72];

    const int tid = threadIdx.x;
    const int wv = tid >> 6, lane = tid & 63, quad = lane >> 4, l16 = lane & 15;
    const int rg = wv >> 2, cg = wv & 3;
    const int row0 = blockIdx.x * 64;

    f32x4 acc[6];                                  // [rt][j] -> acc[rt*3+j]
#pragma unroll
    for (int n = 0; n < 6; n++) acc[n] = (f32x4){0.f, 0.f, 0.f, 0.f};

    float4 xpre[2];
    bf16x8 wpre[3];
#pragma unroll
    for (int k = 0; k < 2; k++) {
        int g = tid + k * 512;
        xpre[k] = *(const float4*)(x + (long)(row0 + (g >> 4)) * 384 + (g & 15) * 4);
    }
#pragma unroll
    for (int k = 0; k < 3; k++)
        wpre[k] = *(const bf16x8*)(Wt + (tid + k * 512) * 8);

    for (int ck = 0; ck < 6; ck++) {
        bf16* Xc = Xs[ck & 1];
        bf16* Wc = Ws[ck & 1];
#pragma unroll
        for (int k = 0; k < 2; k++) {
            int g = tid + k * 512;
            float4 xv = xpre[k];
            *(bf16x4*)(&Xc[(g >> 4) * 72 + (g & 15) * 4]) =
                (bf16x4){(bf16)xv.x, (bf16)xv.y, (bf16)xv.z, (bf16)xv.w};
        }
#pragma unroll
        for (int k = 0; k < 3; k++) {
            int g = tid + k * 512;
            *(bf16x8*)(&Wc[(g >> 3) * 72 + (g & 7) * 8]) = wpre[k];
        }
        if (ck < 5) {
#pragma unroll
            for (int k = 0; k < 2; k++) {
                int g = tid + k * 512;
                xpre[k] = *(const float4*)(x + (long)(row0 + (g >> 4)) * 384 +
                                           (ck + 1) * 64 + (g & 15) * 4);
            }
#pragma unroll
            for (int k = 0; k < 3; k++)
                wpre[k] = *(const bf16x8*)(Wt + (ck + 1) * 12288 + (tid + k * 512) * 8);
        }
        __syncthreads();
#pragma unroll
        for (int kh = 0; kh < 2; kh++) {
            bf16x8 bb[3];
#pragma unroll
            for (int j = 0; j < 3; j++)
                bb[j] = *(bf16x8*)(&Wc[((cg * 3 + j) * 16 + l16) * 72 + kh * 32 + quad * 8]);
#pragma unroll
            for (int rt = 0; rt < 2; rt++) {
                bf16x8 a = *(bf16x8*)(&Xc[(rg * 32 + rt * 16 + l16) * 72 + kh * 32 + quad * 8]);
#pragma unroll
                for (int j = 0; j < 3; j++)
                    acc[rt * 3 + j] = __builtin_amdgcn_mfma_f32_16x16x32_bf16(
                        a, bb[j], acc[rt * 3 + j], 0, 0, 0);
            }
        }
    }

    // epilogue: scatter acc (n = cg*3+j wave-uniform) into staging buffers
    __syncthreads();
#pragma unroll
    for (int rt = 0; rt < 2; rt++) {
#pragma unroll
        for (int j = 0; j < 3; j++) {
            const int n = cg * 3 + j;
            const int drow = rg * 32 + rt * 16 + quad * 4;
#pragma unroll
            for (int r = 0; r < 4; r++) {
                float v = acc[rt * 3 + j][r];
                if (n < 4)
                    Xs[0][(drow + r) * 72 + n * 16 + l16] = (bf16)(v * SCALE_LOG2E);
                else if (n < 8)
                    Xs[1][(drow + r) * 72 + (n - 4) * 16 + l16] = (bf16)v;
                else
                    Ws[0][((n - 8) * 16 + l16) * 72 + drow + r] = (bf16)v;
            }
        }
    }
    __syncthreads();
    const int b = row0 >> 11, t0 = row0 & 2047;
    const int srow = tid >> 3, scb = (tid & 7) * 8;
    *(bf16x8*)(Qb + (long)(row0 + srow) * 64 + scb) =
        *(bf16x8*)(&Xs[0][srow * 72 + scb]);
    *(bf16x8*)(Kb + (long)(row0 + srow) * 64 + scb) =
        *(bf16x8*)(&Xs[1][srow * 72 + scb]);
    *(bf16x8*)(Vtg + (long)(b * 64 + srow) * 2048 + t0 + scb) =
        *(bf16x8*)(&Ws[0][srow * 72 + scb]);
}

// ---------------------------------------------------------------------------
// Kernel 2: flash attention, 512 blocks x 512 thr (8 waves), 16 supersteps
// of 2 k-tiles. Waves 0-3 (S): key-subtile wv; K-direct frags; exp2; Ps
// writes; V staging (both tiles). Waves 4-7 (PV): q-subtile pq; pb/va reads
// + O/l accumulate for tiles 2t-2, 2t-1. ONE barrier per superstep.
// LDS 65536 B: Ps[p] @ p*8192 (Ps[0]=Qs) | Vb[p] @ 32768+p*8192.
//   Om [64][68] f32 overlays @0 (epilogue only, barrier-separated).
// ---------------------------------------------------------------------------
__global__ __launch_bounds__(512, 4) void flash_attn(const bf16* __restrict__ Qb,
                                                     const bf16* __restrict__ Kb,
                                                     const bf16* __restrict__ Vtg,
                                                     float* __restrict__ out) {
    __shared__ __align__(16) char smem[65536];
    bf16* Qs = (bf16*)smem;                   // [64][64]; Ps[0] overlays after hoist

    const int tid = threadIdx.x;
    const int wv = tid >> 6, lane = tid & 63, quad = lane >> 4, l16 = lane & 15;
    const bool sw = (wv < 4);                 // S/staging waves
    const int pq = wv - 4;                    // PV wave's q-tile
    // XCD-aware swizzle: keep a batch's K/V resident in one XCD's L2.
    const int i0 = blockIdx.x;
    const int b = (i0 & 7) + 8 * ((i0 >> 3) >> 5);
    const int qt = (i0 >> 3) & 31;

    const bf16* Qg = Qb + (long)(b * 2048 + qt * 64) * 64;
    const bf16* Kg = Kb + (long)b * 2048 * 64;
    const bf16* Vg = Vtg + (long)b * 64 * 2048;

    // stage Q tile [64][64] (swizzled): 512 thr x 16B
    const int qrow = tid >> 3, qcb = (tid & 7) * 16;
    *(bf16x8*)tp(Qs, qrow, qcb) = *(const bf16x8*)(Qg + qrow * 64 + (qcb >> 1));

    // V staging geometry (S-waves, tid<256): thread covers 2x16B per tile
    const int vrow = tid >> 2, vcb = (tid & 3) * 32;
    // K fragment base (S-waves): ka[j]=K[kt*64+wv*16+l16][kh*32+quad*8+j]
    const bf16* Kfb = Kg + (wv * 16 + l16) * 64 + quad * 8;

    bf16x8 kf[2][2], vp[4];
    if (sw) {
        kf[0][0] = *(const bf16x8*)(Kfb);                 // tile 0
        kf[0][1] = *(const bf16x8*)(Kfb + 32);
        kf[1][0] = *(const bf16x8*)(Kfb + 4096);          // tile 1
        kf[1][1] = *(const bf16x8*)(Kfb + 4096 + 32);
        vp[0] = *(const bf16x8*)(Vg + (long)vrow * 2048 + (vcb >> 1));
        vp[1] = *(const bf16x8*)(Vg + (long)vrow * 2048 + (vcb >> 1) + 8);
        vp[2] = *(const bf16x8*)(Vg + (long)vrow * 2048 + 64 + (vcb >> 1));
        vp[3] = *(const bf16x8*)(Vg + (long)vrow * 2048 + 64 + (vcb >> 1) + 8);
    }

    f32x4 o[4], ol;
#pragma unroll
    for (int n = 0; n < 4; n++) o[n] = (f32x4){0.f, 0.f, 0.f, 0.f};
    ol = (f32x4){0.f, 0.f, 0.f, 0.f};

    __syncthreads();            // Qs staged
    // hoist Q^T b-frags (S-waves only; loop-invariant)
    bf16x8 qb[4][2];
    if (sw) {
#pragma unroll
        for (int nt = 0; nt < 4; nt++)
#pragma unroll
            for (int kh = 0; kh < 2; kh++)
                qb[nt][kh] = *(bf16x8*)tp(Qs, nt * 16 + l16, kh * 64 + quad * 16);
    }
    __syncthreads();            // hoist done before Ps[0] (=Qs) writes

    const bf16 one = (bf16)1.0f;
    const bf16x8 ones = {one, one, one, one, one, one, one, one};

#pragma unroll 2
    for (int t = 0; t < 16; t++) {
        const int sel = (t & 1) ? 16384 : 0;          // phase of tile 2t
        bf16* PsW0 = (bf16*)(smem + sel);             // Ps[2t&3]
        bf16* PsW1 = (bf16*)(smem + sel + 8192);      // Ps[(2t+1)&3]
        bf16* PsR0 = (bf16*)(smem + (16384 - sel));   // Ps[(2t-2)&3]
        bf16* PsR1 = (bf16*)(smem + (16384 - sel) + 8192);
        bf16* VW0 = (bf16*)(smem + 32768 + sel);
        bf16* VW1 = (bf16*)(smem + 32768 + sel + 8192);
        bf16* VR0 = (bf16*)(smem + 32768 + (16384 - sel));
        bf16* VR1 = (bf16*)(smem + 32768 + (16384 - sel) + 8192);

        if (sw) {
            // commit V[2t], V[2t+1] (regions not read this superstep)
            *(bf16x8*)tp(VW0, vrow, vcb)      = vp[0];
            *(bf16x8*)tp(VW0, vrow, vcb + 16) = vp[1];
            *(bf16x8*)tp(VW1, vrow, vcb)      = vp[2];
            *(bf16x8*)tp(VW1, vrow, vcb + 16) = vp[3];

            // S for tile 2t (kf[0])
            f32x4 s[4];
#pragma unroll
            for (int nt = 0; nt < 4; nt++) s[nt] = (f32x4){0.f, 0.f, 0.f, 0.f};
            __builtin_amdgcn_s_setprio(1);
#pragma unroll
            for (int kh = 0; kh < 2; kh++) {
                bf16x8 ka = kf[0][kh];
#pragma unroll
                for (int nt = 0; nt < 4; nt++)
                    s[nt] = __builtin_amdgcn_mfma_f32_16x16x32_bf16(ka, qb[nt][kh], s[nt], 0, 0, 0);
            }
            __builtin_amdgcn_s_setprio(0);
            // reload kf[0] <- tile 2t+2 (consumed next superstep, ~900cy away)
            if (t < 15) {
                kf[0][0] = *(const bf16x8*)(Kfb + (long)(2 * t + 2) * 4096);
                kf[0][1] = *(const bf16x8*)(Kfb + (long)(2 * t + 2) * 4096 + 32);
            }
#pragma unroll
            for (int nt = 0; nt < 4; nt++) {
                bf16x4 pp;
#pragma unroll
                for (int r = 0; r < 4; r++)
                    pp[r] = (bf16)__builtin_amdgcn_exp2f(s[nt][r]);
                *(bf16x4*)tp(PsW0, nt * 16 + l16, wv * 32 + quad * 8) = pp;
            }

            // S for tile 2t+1 (kf[1])
#pragma unroll
            for (int nt = 0; nt < 4; nt++) s[nt] = (f32x4){0.f, 0.f, 0.f, 0.f};
            __builtin_amdgcn_s_setprio(1);
#pragma unroll
            for (int kh = 0; kh < 2; kh++) {
                bf16x8 ka = kf[1][kh];
#pragma unroll
                for (int nt = 0; nt < 4; nt++)
                    s[nt] = __builtin_amdgcn_mfma_f32_16x16x32_bf16(ka, qb[nt][kh], s[nt], 0, 0, 0);
            }
            __builtin_amdgcn_s_setprio(0);
            // reload kf[1] + vp <- tiles 2t+2 / 2t+3
            if (t < 15) {
                kf[1][0] = *(const bf16x8*)(Kfb + (long)(2 * t + 3) * 4096);
                kf[1][1] = *(const bf16x8*)(Kfb + (long)(2 * t + 3) * 4096 + 32);
                vp[0] = *(const bf16x8*)(Vg + (long)vrow * 2048 + (2 * t + 2) * 64 + (vcb >> 1));
                vp[1] = *(const bf16x8*)(Vg + (long)vrow * 2048 + (2 * t + 2) * 64 + (vcb >> 1) + 8);
                vp[2] = *(const bf16x8*)(Vg + (long)vrow * 2048 + (2 * t + 3) * 64 + (vcb >> 1));
                vp[3] = *(const bf16x8*)(Vg + (long)vrow * 2048 + (2 * t + 3) * 64 + (vcb >> 1) + 8);
            }
#pragma unroll
            for (int nt = 0; nt < 4; nt++) {
                bf16x4 pp;
#pragma unroll
                for (int r = 0; r < 4; r++)
                    pp[r] = (bf16)__builtin_amdgcn_exp2f(s[nt][r]);
                *(bf16x4*)tp(PsW1, nt * 16 + l16, wv * 32 + quad * 8) = pp;
            }
        } else if (t) {
            // PV for tiles 2t-2 and 2t-1 : this wave's q subtile (n=pq)
            __builtin_amdgcn_s_setprio(1);
#pragma unroll
            for (int kh = 0; kh < 2; kh++) {
                bf16x8 pb = *(bf16x8*)tp(PsR0, pq * 16 + l16, kh * 64 + quad * 16);
#pragma unroll
                for (int mt = 0; mt < 4; mt++) {
                    bf16x8 va = *(bf16x8*)tp(VR0, mt * 16 + l16, kh * 64 + quad * 16);
                    o[mt] = __builtin_amdgcn_mfma_f32_16x16x32_bf16(va, pb, o[mt], 0, 0, 0);
                }
                ol = __builtin_amdgcn_mfma_f32_16x16x32_bf16(ones, pb, ol, 0, 0, 0);
            }
#pragma unroll
            for (int kh = 0; kh < 2; kh++) {
                bf16x8 pb = *(bf16x8*)tp(PsR1, pq * 16 + l16, kh * 64 + quad * 16);
#pragma unroll
                for (int mt = 0; mt < 4; mt++) {
                    bf16x8 va = *(bf16x8*)tp(VR1, mt * 16 + l16, kh * 64 + quad * 16);
                    o[mt] = __builtin_amdgcn_mfma_f32_16x16x32_bf16(va, pb, o[mt], 0, 0, 0);
                }
                ol = __builtin_amdgcn_mfma_f32_16x16x32_bf16(ones, pb, ol, 0, 0, 0);
            }
            __builtin_amdgcn_s_setprio(0);
        }
        __syncthreads();        // one barrier: publishes V[2t],V[2t+1],Ps both
    }

    // peeled PV for tiles 30 (phase 2) and 31 (phase 3)
    if (!sw) {
#pragma unroll
        for (int pt = 0; pt < 2; pt++) {
            bf16* Pr = (bf16*)(smem + 16384 + pt * 8192);
            bf16* Vp = (bf16*)(smem + 49152 + pt * 8192);
#pragma unroll
            for (int kh = 0; kh < 2; kh++) {
                bf16x8 pb = *(bf16x8*)tp(Pr, pq * 16 + l16, kh * 64 + quad * 16);
#pragma unroll
                for (int mt = 0; mt < 4; mt++) {
                    bf16x8 va = *(bf16x8*)tp(Vp, mt * 16 + l16, kh * 64 + quad * 16);
                    o[mt] = __builtin_amdgcn_mfma_f32_16x16x32_bf16(va, pb, o[mt], 0, 0, 0);
                }
                ol = __builtin_amdgcn_mfma_f32_16x16x32_bf16(ones, pb, ol, 0, 0, 0);
            }
        }
    }

    // epilogue: PV lanes hold l(q) in ol[*]; normalize, transpose via LDS
    float inv = 1.0f / ol[0];
    __syncthreads();            // peeled reads done before Om overlay
    float* Om = (float*)smem;                 // [64][68] floats (17408 B)
    if (!sw) {
#pragma unroll
        for (int mt = 0; mt < 4; mt++) {
            f32x4 ov;
#pragma unroll
            for (int r = 0; r < 4; r++) ov[r] = o[mt][r] * inv;
            *(f32x4*)(&Om[(pq * 16 + l16) * 68 + mt * 16 + quad * 4]) = ov;
        }
    }
    __syncthreads();
    const int orow = tid >> 3, ocf = (tid & 7) * 8;
    float* og = out + (long)(b * 2048 + qt * 64 + orow) * 64 + ocf;
#pragma unroll
    for (int j = 0; j < 2; j++)
        *(float4*)(og + j * 4) = *(float4*)(&Om[orow * 68 + ocf + j * 4]);
}

// ---------------------------------------------------------------------------
extern "C" void kernel_launch(void* const* d_in, const int* in_sizes, int n_in,
                              void* d_out, int out_size, void* d_ws, size_t ws_size,
                              hipStream_t stream) {
    const float* x  = (const float*)d_in[0];
    const float* Wq = (const float*)d_in[1];
    const float* Wk = (const float*)d_in[2];
    const float* Wv = (const float*)d_in[3];
    float* out = (float*)d_out;

    bf16* Qb  = (bf16*)d_ws;           // 32768*64
    bf16* Kb  = Qb + 2097152;
    bf16* Vtg = Kb + 2097152;          // [16][64][2048]
    bf16* Wt  = Vtg + 2097152;         // 6*192*64

    pack_w<<<288, 256, 0, stream>>>(Wq, Wk, Wv, Wt);
    qkv_proj<<<512, 512, 0, stream>>>(x, Wt, Qb, Kb, Vtg);
    flash_attn<<<512, 512, 0, stream>>>(Qb, Kb, Vtg, out);
}